// Round 16
// baseline (481.722 us; speedup 1.0000x reference)
//
#include <hip/hip_runtime.h>
#include <math.h>

namespace {

constexpr int BATCH = 2;
constexpr int NTOK  = 8192;    // tokens per batch (T*H*W)
constexpr int MROWS = 16384;   // BATCH*NTOK
constexpr int C     = 512;
constexpr int GH    = 8;
constexpr int DH    = 32;
constexpr int WIN   = 64;
constexpr int NW    = 128;     // NTOK/WIN
constexpr int FF    = 1024;
constexpr int NBF   = 110;     // int(32*ln(32))
constexpr int NBFP  = 128;     // padded feature count (MFMA tiles)

constexpr float F_DN     = 0.42044820762685725f;   // 32^-0.25
constexpr float F_RNORM  = 0.09534625892455924f;   // 110^-0.5
constexpr float F_LSCALE = 0.17677669529663687f;   // 32^-0.5

typedef __attribute__((ext_vector_type(8))) short bf16x8;
typedef __attribute__((ext_vector_type(4))) float f32x4;

__device__ __forceinline__ ushort f2b(float f){
  unsigned u = __float_as_uint(f);
  unsigned r = u + 0x7FFFu + ((u >> 16) & 1u);
  return (ushort)(r >> 16);
}
__device__ __forceinline__ float b2f(ushort u){
  return __uint_as_float((unsigned)u << 16);
}

__device__ __forceinline__ void gload16(const void* g, void* l){
  __builtin_amdgcn_global_load_lds((const __attribute__((address_space(1))) void*)g,
                                   (__attribute__((address_space(3))) void*)l, 16, 0, 0);
}

__global__ void k_tables(float* __restrict__ cost, float* __restrict__ sint){
  int idx = blockIdx.x*256 + threadIdx.x;
  if (idx >= NTOK*16) return;
  int pos = idx >> 4, f = idx & 15;
  float inv = powf(10000.f, -(float)f/16.f);
  float ang = (float)pos * inv;
  cost[idx] = cosf(ang);
  sint[idx] = sinf(ang);
}

// All 12 weight matrices (both layers) fp32 (K,N) -> bf16 transposed (N,K), one dispatch.
__global__ __launch_bounds__(256) void k_wcvt_all(const float* __restrict__ Wq, const float* __restrict__ Wk,
     const float* __restrict__ Wv, const float* __restrict__ Wo, const float* __restrict__ W1,
     const float* __restrict__ W2, ushort* __restrict__ wt){
  __shared__ float t[32][33];
  int id = blockIdx.x;
  int l = id >> 11;
  int r = id & 2047;
  const float* src; ushort* dst; int K, N, bx, by;
  if (r < 1024){
    int mat = r >> 8, tt = r & 255;
    bx = tt & 15; by = tt >> 4; K = 512; N = 512;
    src = ((mat == 0) ? Wq : (mat == 1) ? Wk : (mat == 2) ? Wv : Wo) + (size_t)l*262144;
    dst = wt + (size_t)l*2097152 + (size_t)mat*262144;
  } else if (r < 1536){
    int tt = r - 1024;
    bx = tt & 31; by = tt >> 5; K = 512; N = 1024;
    src = W1 + (size_t)l*524288;
    dst = wt + (size_t)l*2097152 + 1048576;
  } else {
    int tt = r - 1536;
    bx = tt & 15; by = tt >> 4; K = 1024; N = 512;
    src = W2 + (size_t)l*524288;
    dst = wt + (size_t)l*2097152 + 1572864;
  }
  int tx = threadIdx.x & 31, ty = threadIdx.x >> 5;
  #pragma unroll
  for (int rr = ty; rr < 32; rr += 8) t[rr][tx] = src[(size_t)(by*32+rr)*N + bx*32 + tx];
  __syncthreads();
  #pragma unroll
  for (int rr = ty; rr < 32; rr += 8) dst[(size_t)(bx*32+rr)*K + by*32 + tx] = f2b(t[tx][rr]);
}

// LayerNorm; INBF: input is bf16 (residual stream) vs fp32.
template<int INBF>
__global__ __launch_bounds__(256) void k_ln(const void* __restrict__ xv, const float* __restrict__ g,
                     const float* __restrict__ b, ushort* __restrict__ y){
  int row = blockIdx.x, t = threadIdx.x;
  float2 v;
  if (INBF){
    ushort2 u = *(const ushort2*)((const ushort*)xv + (size_t)row*C + 2*t);
    v.x = b2f(u.x); v.y = b2f(u.y);
  } else {
    v = *(const float2*)((const float*)xv + (size_t)row*C + 2*t);
  }
  float s = v.x + v.y, ss = v.x*v.x + v.y*v.y;
  #pragma unroll
  for (int o = 32; o; o >>= 1){ s += __shfl_down(s, o); ss += __shfl_down(ss, o); }
  __shared__ float rs[4], rss[4];
  int wv = t >> 6, ln = t & 63;
  if (ln == 0){ rs[wv] = s; rss[wv] = ss; }
  __syncthreads();
  float S = rs[0]+rs[1]+rs[2]+rs[3], SS = rss[0]+rss[1]+rss[2]+rss[3];
  float mean = S * (1.f/C);
  float var  = SS * (1.f/C) - mean*mean;
  float rstd = rsqrtf(var + 1e-5f);
  float2 gg = *(const float2*)(g + 2*t);
  float2 bb = *(const float2*)(b + 2*t);
  ushort2 ov;
  ov.x = f2b((v.x - mean)*rstd*gg.x + bb.x);
  ov.y = f2b((v.y - mean)*rstd*gg.y + bb.y);
  *(ushort2*)(y + (size_t)row*C + 2*t) = ov;
}

// bf16 MFMA GEMM v3: 256x128 tile, 8 waves (512 thr), 2-phase dbuf (R11 discipline),
// T1 XCD swizzle, T2-lite LDS XOR swizzle: byte-bits 4-5 of each tile row are XORed
// with row&3 (involution). gload_lds keeps a LINEAR dest; the per-lane GLOBAL source
// k-chunk is pre-permuted (same 64B row segment, so coalescing unchanged); frag reads
// use chunk g^(c&3). Fragment-read conflicts drop 8-way -> 4-way.
// A: (M,K) bf16 row-major.  Bt: (N,K) bf16 row-major.  grid (Nd/128, M/256).
// QKV==1: Nd=1536 logical; de-interleave into 3 (M,512) buffers + fused RoPE.
template<int ACT, int OBF, int QKV, int RESBF>
__global__ __launch_bounds__(512) void k_mgemm(const ushort* __restrict__ A, const ushort* __restrict__ Bt,
      const float* __restrict__ bias, const float* __restrict__ bias2, const float* __restrict__ bias3,
      const void* __restrict__ res, float* __restrict__ outf, ushort* __restrict__ outb,
      const float* __restrict__ cosT, const float* __restrict__ sinT, int Nd, int Kd){
  __shared__ ushort As[2][256*32];   // 16KB per buffer
  __shared__ ushort Bs[2][128*32];   //  8KB per buffer
  int tid = threadIdx.x;
  int lane = tid & 63, wave = tid >> 6;      // 8 waves
  int c = lane & 15, g = lane >> 4;
  int wr = wave >> 1, wc = wave & 1;         // 4M x 2N wave grid
  int swk = g ^ (c & 3);                     // swizzled k-chunk for frag reads
  // T1: XCD-bijective swizzle (all grids have nwg % 8 == 0).
  int gx = gridDim.x;
  int nwg = gx * (int)gridDim.y;
  int bid = (int)(blockIdx.y*gx + blockIdx.x);
  int swz = (bid & 7)*(nwg >> 3) + (bid >> 3);
  int row0 = (swz / gx)*256, col0 = (swz % gx)*128;
  f32x4 acc[4][4] = {};
  int nt = Kd >> 5;

  // LDS chunk pc (linear) holds global (row=pc>>2, kchunk=(pc&3)^(row&3)).
  #define STAGE(buf, kt) {                                                        \
    int k0_ = (kt)*32;                                                            \
    _Pragma("unroll")                                                             \
    for (int j = 0; j < 2; j++){                                                  \
      int ci = j*512 + tid;                                                       \
      int r_ = ci >> 2, kc_ = (ci & 3) ^ (r_ & 3);                                \
      gload16(A + (size_t)(row0 + r_)*Kd + k0_ + kc_*8,                           \
              (char*)As[buf] + (j*512 + wave*64)*16);                             \
    }                                                                             \
    {                                                                             \
      int ci = tid;                                                               \
      int r_ = ci >> 2, kc_ = (ci & 3) ^ (r_ & 3);                                \
      gload16(Bt + (size_t)(col0 + r_)*Kd + k0_ + kc_*8,                          \
              (char*)Bs[buf] + (wave*64)*16);                                     \
    }                                                                             \
  }

  STAGE(0, 0);
  __syncthreads();                                  // drain tile-0 loads

  for (int t = 0; t < nt; t++){
    int cur = t & 1;
    bf16x8 af[4], bfr[4];
    #pragma unroll
    for (int m = 0; m < 4; m++)
      af[m] = *(const bf16x8*)(As[cur] + (wr*64 + m*16 + c)*32 + swk*8);
    #pragma unroll
    for (int n = 0; n < 4; n++)
      bfr[n] = *(const bf16x8*)(Bs[cur] + (wc*64 + n*16 + c)*32 + swk*8);
    if (t + 1 < nt) STAGE(cur^1, t+1);              // loads fly under the MFMAs
    __builtin_amdgcn_s_setprio(1);
    #pragma unroll
    for (int m = 0; m < 4; m++)
      #pragma unroll
      for (int n = 0; n < 4; n++)
        acc[m][n] = __builtin_amdgcn_mfma_f32_16x16x32_bf16(af[m], bfr[n], acc[m][n], 0, 0, 0);
    __builtin_amdgcn_s_setprio(0);
    __syncthreads();                                // post-MFMA drain + LDS reuse barrier
  }
  #undef STAGE

  if (QKV){
    #pragma unroll
    for (int m = 0; m < 4; m++){
      int rbase = row0 + wr*64 + m*16 + g*4;
      #pragma unroll
      for (int np = 0; np < 2; np++){
        int n0 = 2*np, n1 = n0 + 1;
        int ccol = col0 + wc*64 + n0*16 + c;           // ccol&31 == c (<16)
        int bid2 = ccol >> 9;
        int cl  = ccol & 511;
        const float* bp = (bid2 == 0) ? bias : (bid2 == 1) ? bias2 : bias3;
        float b0 = bp[cl], b1 = bp[cl+16];
        bool dorope = (bid2 < 2) && (cl >= 256);
        ushort* obase = outb + (size_t)bid2*MROWS*C;
        #pragma unroll
        for (int r = 0; r < 4; r++){
          int grow = rbase + r;
          float a  = acc[m][n0][r] + b0;
          float bb = acc[m][n1][r] + b1;
          if (dorope){
            int pos = grow & (NTOK-1);
            float cv = cosT[pos*16 + c], sv = sinT[pos*16 + c];
            float na = a*cv - bb*sv;
            float nb = bb*cv + a*sv;
            a = na; bb = nb;
          }
          obase[(size_t)grow*C + cl]      = f2b(a);
          obase[(size_t)grow*C + cl + 16] = f2b(bb);
        }
      }
    }
    return;
  }
  #pragma unroll
  for (int m = 0; m < 4; m++){
    int rbase = row0 + wr*64 + m*16 + g*4;
    #pragma unroll
    for (int n = 0; n < 4; n++){
      int ccol = col0 + wc*64 + n*16 + c;
      float bv = bias[ccol];
      #pragma unroll
      for (int r = 0; r < 4; r++){
        int grow = rbase + r;
        float vv = acc[m][n][r] + bv;
        if (ACT == 1) vv = 0.5f*vv*(1.f + erff(vv*0.7071067811865476f));
        if (res){
          size_t ri = (size_t)grow*Nd + ccol;
          vv += RESBF ? b2f(((const ushort*)res)[ri]) : ((const float*)res)[ri];
        }
        if (OBF) outb[(size_t)grow*Nd + ccol] = f2b(vv);
        else     outf[(size_t)grow*Nd + ccol] = vv;
      }
    }
  }
}

// Performer K side v4 (MFMA, no global-stab pass). Block = (bh, 256 k-rows); 4 waves.
__global__ __launch_bounds__(256) void k_ctx3(const ushort* __restrict__ k, const ushort* __restrict__ v,
        const float* __restrict__ proj, float* __restrict__ ctxp, float* __restrict__ ksump){
  int bh = blockIdx.x >> 5, chunk = blockIdx.x & 31;
  int b = bh >> 3, h = bh & 7;
  __shared__ __align__(16) ushort pl[NBFP*40];   // proj bf16 [feat][40 pad]  10.0KB
  __shared__ __align__(16) ushort Ps[NBFP*72];   // P [feat][64+8 pad]        18.0KB
  __shared__ __align__(16) ushort Vt[48*72];     // V^T slice [48][72]         6.75KB
  __shared__ float dgl[256];
  int tid = threadIdx.x;
  int lane = tid & 63, wave = tid >> 6;
  int c = lane & 15, g = lane >> 4;
  int i0 = chunk*256;

  for (int idx = tid; idx < NBFP*32; idx += 256){
    int f = idx >> 5, d = idx & 31;
    pl[f*40 + d] = (f < NBF) ? f2b(proj[f*32 + d]*F_DN) : (ushort)0;
  }
  const ushort* kbase = k + ((size_t)b*NTOK + i0)*C + h*DH;
  const ushort* vbase = v + ((size_t)b*NTOK + i0)*C + h*DH;
  #pragma unroll
  for (int s = 0; s < 4; s++){
    bf16x8 kf = *(const bf16x8*)(kbase + (size_t)(s*64 + wave*16 + c)*C + g*8);
    const ushort* kp_ = (const ushort*)&kf;
    float sq = 0.f;
    #pragma unroll
    for (int j = 0; j < 8; j++){ float vv = b2f(kp_[j]); sq += vv*vv; }
    sq += __shfl_xor(sq, 16);
    sq += __shfl_xor(sq, 32);
    if (g == 0) dgl[s*64 + wave*16 + c] = 0.5f*F_DN*F_DN*sq;
  }
  for (int idx = tid; idx < 15*72; idx += 256) Vt[33*72 + idx] = 0;   // zero rows 33..47

  f32x4 zz = {0.f, 0.f, 0.f, 0.f};
  f32x4 acc[2][3] = {};

  for (int s = 0; s < 4; s++){
    __syncthreads();     // Ps/Vt free (also covers pl/dgl/Vt-zero init at s=0)
    {
      int r = tid >> 2, part = tid & 3;
      uint4 vv = *(const uint4*)(vbase + (size_t)(s*64 + r)*C + part*8);
      const ushort* vp = (const ushort*)&vv;
      #pragma unroll
      for (int j = 0; j < 8; j++) Vt[(part*8+j)*72 + r] = vp[j];
      if (tid < 64) Vt[32*72 + tid] = 0x3F80;   // bf16 1.0
    }
    bf16x8 af = *(const bf16x8*)(kbase + (size_t)(s*64 + wave*16 + c)*C + g*8);
    #pragma unroll
    for (int ft = 0; ft < 8; ft++){
      bf16x8 bf = *(const bf16x8*)(pl + (ft*16 + c)*40 + g*8);
      f32x4 dd = __builtin_amdgcn_mfma_f32_16x16x32_bf16(af, bf, zz, 0, 0, 0);
      int feat = ft*16 + c;
      bool fvalid = feat < NBF;
      ushort pb[4];
      #pragma unroll
      for (int r = 0; r < 4; r++){
        float kp = 0.f;
        if (fvalid){
          float dg_ = dgl[s*64 + wave*16 + g*4 + r];
          kp = F_RNORM*(__expf(dd[r] - dg_) + 1e-4f);
        }
        pb[r] = f2b(kp);
      }
      uint2 pd;
      pd.x = (unsigned)pb[0] | ((unsigned)pb[1] << 16);
      pd.y = (unsigned)pb[2] | ((unsigned)pb[3] << 16);
      *(uint2*)(Ps + (ft*16 + c)*72 + wave*16 + g*4) = pd;
    }
    __syncthreads();
    #pragma unroll
    for (int i = 0; i < 2; i++){
      int ft = wave*2 + i;
      #pragma unroll
      for (int kk = 0; kk < 2; kk++){
        bf16x8 ap = *(const bf16x8*)(Ps + (ft*16 + c)*72 + kk*32 + g*8);
        #pragma unroll
        for (int nt = 0; nt < 3; nt++){
          bf16x8 bv = *(const bf16x8*)(Vt + (nt*16 + c)*72 + kk*32 + g*8);
          acc[i][nt] = __builtin_amdgcn_mfma_f32_16x16x32_bf16(ap, bv, acc[i][nt], 0, 0, 0);
        }
      }
    }
  }
  size_t pbase = (size_t)(bh*32 + chunk)*NBF;
  #pragma unroll
  for (int i = 0; i < 2; i++){
    int ftb = (wave*2 + i)*16;
    #pragma unroll
    for (int r = 0; r < 4; r++){
      int feat = ftb + g*4 + r;
      if (feat < NBF){
        #pragma unroll
        for (int nt = 0; nt < 2; nt++)
          ctxp[(pbase + feat)*DH + nt*16 + c] = acc[i][nt][r];
        if (c == 0) ksump[pbase + feat] = acc[i][2][r];
      }
    }
  }
}

__global__ void k_ctxred(const float* __restrict__ ctxp, const float* __restrict__ ksump,
                         float* __restrict__ ctx, float* __restrict__ ksum){
  int bh = blockIdx.x / NBF, m = blockIdx.x % NBF;
  int t = threadIdx.x;
  if (t < DH){
    float s = 0.f;
    for (int c = 0; c < 32; c++) s += ctxp[((size_t)(bh*32 + c)*NBF + m)*DH + t];
    ctx[((size_t)bh*NBF + m)*DH + t] = s;
  } else if (t == DH){
    float s = 0.f;
    for (int c = 0; c < 32; c++) s += ksump[(size_t)(bh*32 + c)*NBF + m];
    ksum[bh*NBF + m] = s;
  }
}

// Performer Q side v3 (MFMA). One block per (bh, 64 q-rows); 4 waves.
__global__ __launch_bounds__(256) void k_qattn3(const ushort* __restrict__ q, const float* __restrict__ proj,
        const float* __restrict__ ctx, const float* __restrict__ ksum, ushort* __restrict__ o){
  int bh = blockIdx.x >> 7, chunk = blockIdx.x & 127;
  int b = bh >> 3, h = bh & 7;
  __shared__ __align__(16) ushort pl[NBFP*40];    // proj bf16 [feat][40 pad]   10.0KB
  __shared__ __align__(16) ushort ql[64*40];      // Q [qrow][40 pad]            5.0KB
  __shared__ __align__(16) ushort ctl[32*136];    // ctx^T [d][136 pad]          8.5KB
  __shared__ __align__(16) ushort Ps[64*136];     // P [qrow][136 pad]          17.0KB
  __shared__ float ksl[NBFP];
  __shared__ float dgl[64];
  __shared__ float dvl[64];
  int tid = threadIdx.x;
  int lane = tid & 63, wave = tid >> 6;
  int c = lane & 15, g = lane >> 4;
  int i0 = chunk*64;

  for (int idx = tid; idx < NBFP*32; idx += 256){
    int f = idx >> 5, d = idx & 31;
    pl[f*40 + d] = (f < NBF) ? f2b(proj[f*32 + d]*F_DN) : (ushort)0;
  }
  {
    int row = tid >> 2, part = tid & 3;
    uint4 qq = *(const uint4*)(q + (size_t)(b*NTOK + i0 + row)*C + h*DH + part*8);
    *(uint4*)(ql + row*40 + part*8) = qq;
    const ushort* qp_ = (const ushort*)&qq;
    float sq = 0.f;
    #pragma unroll
    for (int j = 0; j < 8; j++){ float vv = b2f(qp_[j]); sq += vv*vv; }
    sq += __shfl_xor(sq, 1);
    sq += __shfl_xor(sq, 2);
    if (part == 0) dgl[row] = 0.5f*F_DN*F_DN*sq;
  }
  for (int idx = tid; idx < 32*NBFP; idx += 256){
    int d = idx >> 7, f = idx & 127;
    float vv = (f < NBF) ? ctx[((size_t)bh*NBF + f)*DH + d] : 0.f;
    ctl[d*136 + f] = f2b(vv);
  }
  if (tid < NBFP) ksl[tid] = (tid < NBF) ? ksum[bh*NBF + tid] : 0.f;
  __syncthreads();

  f32x4 zz = {0.f, 0.f, 0.f, 0.f};
  bf16x8 qf = *(const bf16x8*)(ql + (wave*16 + c)*40 + g*8);
  f32x4 st[8];
  #pragma unroll
  for (int mt = 0; mt < 8; mt++){
    bf16x8 af = *(const bf16x8*)(pl + (mt*16 + c)*40 + g*8);
    st[mt] = __builtin_amdgcn_mfma_f32_16x16x32_bf16(af, qf, zz, 0, 0, 0);
  }
  float mx = -1e30f;
  #pragma unroll
  for (int mt = 0; mt < 8; mt++)
    #pragma unroll
    for (int r = 0; r < 4; r++){
      int feat = mt*16 + g*4 + r;
      if (feat < NBF) mx = fmaxf(mx, st[mt][r]);
    }
  mx = fmaxf(mx, __shfl_xor(mx, 16));
  mx = fmaxf(mx, __shfl_xor(mx, 32));
  float diagv = dgl[wave*16 + c];
  float dv = 0.f;
  #pragma unroll
  for (int mt = 0; mt < 8; mt++){
    ushort pb[4];
    #pragma unroll
    for (int r = 0; r < 4; r++){
      int feat = mt*16 + g*4 + r;
      float qp = 0.f;
      if (feat < NBF) qp = F_RNORM*(__expf(st[mt][r] - diagv - mx) + 1e-4f);
      ushort qb = f2b(qp);
      pb[r] = qb;
      dv += b2f(qb)*ksl[feat];
    }
    uint2 pd;
    pd.x = (unsigned)pb[0] | ((unsigned)pb[1] << 16);
    pd.y = (unsigned)pb[2] | ((unsigned)pb[3] << 16);
    *(uint2*)(Ps + (wave*16 + c)*136 + mt*16 + g*4) = pd;
  }
  dv += __shfl_xor(dv, 16);
  dv += __shfl_xor(dv, 32);
  if (g == 0) dvl[wave*16 + c] = 1.f/dv;
  __syncthreads();

  #pragma unroll
  for (int n = 0; n < 2; n++){
    f32x4 acc = zz;
    #pragma unroll
    for (int kk = 0; kk < 4; kk++){
      bf16x8 ap = *(const bf16x8*)(Ps  + (wave*16 + c)*136 + kk*32 + g*8);
      bf16x8 bc = *(const bf16x8*)(ctl + (n*16 + c)*136    + kk*32 + g*8);
      acc = __builtin_amdgcn_mfma_f32_16x16x32_bf16(ap, bc, acc, 0, 0, 0);
    }
    #pragma unroll
    for (int r = 0; r < 4; r++){
      int qrow = wave*16 + g*4 + r;
      float val = acc[r]*dvl[qrow];
      o[(size_t)(b*NTOK + i0 + qrow)*C + h*DH + n*16 + c] = f2b(val);
    }
  }
}

// Local windowed attention via MFMA. One block per (b, head, window); 4 waves x 16 q-rows.
__global__ __launch_bounds__(256) void k_local2(const ushort* __restrict__ q, const ushort* __restrict__ k,
        const ushort* __restrict__ v, ushort* __restrict__ o){
  int blk = blockIdx.x;
  int w = blk & (NW-1);
  int rem = blk >> 7;
  int hl = rem & 7, b = rem >> 3;
  int hd = GH + hl;
  __shared__ __align__(16) ushort Ks[192*32];      // [key][d]        12.0KB
  __shared__ __align__(16) ushort Vt[32*200];      // [d][key] pad    12.5KB
  __shared__ __align__(16) ushort Ps[4*16*200];    // per-wave [q][key] pad 25KB
  int tid = threadIdx.x;
  int lane = tid & 63, wave = tid >> 6;
  int c = lane & 15, g = lane >> 4;

  const ushort* kbase = k + (size_t)b*NTOK*C + hd*DH;
  const ushort* vbase = v + (size_t)b*NTOK*C + hd*DH;
  #pragma unroll
  for (int s = 0; s < 3; s++){
    int ch = tid + s*256;
    int row = ch >> 2, part = ch & 3;
    int kp = min(max((w-1)*WIN + row, 0), NTOK-1);
    gload16(kbase + (size_t)kp*C + part*8, (char*)Ks + (s*256 + wave*64)*16);
  }
  #pragma unroll
  for (int s = 0; s < 3; s++){
    int ch = tid + s*256;
    int row = ch >> 2, part = ch & 3;
    int kp = min(max((w-1)*WIN + row, 0), NTOK-1);
    uint4 vv = *(const uint4*)(vbase + (size_t)kp*C + part*8);
    const ushort* vp = (const ushort*)&vv;
    #pragma unroll
    for (int j = 0; j < 8; j++) Vt[(part*8+j)*200 + row] = vp[j];
  }
  int qrow = w*WIN + wave*16 + c;
  bf16x8 qf = *(const bf16x8*)(q + ((size_t)b*NTOK + qrow)*C + hd*DH + g*8);
  asm volatile("s_waitcnt vmcnt(0)" ::: "memory");
  __syncthreads();

  f32x4 zz = {0.f, 0.f, 0.f, 0.f};
  f32x4 st[12];
  #pragma unroll
  for (int t = 0; t < 12; t++){
    bf16x8 af = *(const bf16x8*)(Ks + (16*t + c)*32 + g*8);
    st[t] = __builtin_amdgcn_mfma_f32_16x16x32_bf16(af, qf, zz, 0, 0, 0);
  }
  int t0 = (w == 0) ? 4 : 0;
  int t1 = (w == NW-1) ? 8 : 12;
  float lsum = 0.f;
  ushort* pw = Ps + wave*3200 + c*200;
  #pragma unroll
  for (int t = 0; t < 12; t++){
    bool valid = (t >= t0) && (t < t1);
    float p0 = valid ? __expf(st[t][0]*F_LSCALE) : 0.f;
    float p1 = valid ? __expf(st[t][1]*F_LSCALE) : 0.f;
    float p2 = valid ? __expf(st[t][2]*F_LSCALE) : 0.f;
    float p3 = valid ? __expf(st[t][3]*F_LSCALE) : 0.f;
    lsum += (p0+p1)+(p2+p3);
    uint2 pd;
    pd.x = (unsigned)f2b(p0) | ((unsigned)f2b(p1) << 16);
    pd.y = (unsigned)f2b(p2) | ((unsigned)f2b(p3) << 16);
    *(uint2*)(pw + 16*t + 4*g) = pd;
  }
  lsum += __shfl_xor(lsum, 16);
  lsum += __shfl_xor(lsum, 32);

  f32x4 oc0 = zz, oc1 = zz;
  #pragma unroll
  for (int kb = 0; kb < 6; kb++){
    bf16x8 pf = *(const bf16x8*)(pw + kb*32 + g*8);
    bf16x8 v0 = *(const bf16x8*)(Vt + c*200 + kb*32 + g*8);
    bf16x8 v1 = *(const bf16x8*)(Vt + (16 + c)*200 + kb*32 + g*8);
    oc0 = __builtin_amdgcn_mfma_f32_16x16x32_bf16(v0, pf, oc0, 0, 0, 0);
    oc1 = __builtin_amdgcn_mfma_f32_16x16x32_bf16(v1, pf, oc1, 0, 0, 0);
  }
  float inv = 1.f/lsum;
  ushort* orow = o + ((size_t)b*NTOK + qrow)*C + hd*DH;
  uint2 w0, w1;
  w0.x = (unsigned)f2b(oc0[0]*inv) | ((unsigned)f2b(oc0[1]*inv) << 16);
  w0.y = (unsigned)f2b(oc0[2]*inv) | ((unsigned)f2b(oc0[3]*inv) << 16);
  w1.x = (unsigned)f2b(oc1[0]*inv) | ((unsigned)f2b(oc1[1]*inv) << 16);
  w1.y = (unsigned)f2b(oc1[2]*inv) | ((unsigned)f2b(oc1[3]*inv) << 16);
  *(uint2*)(orow + 4*g)      = w0;
  *(uint2*)(orow + 16 + 4*g) = w1;
}

} // namespace

extern "C" void kernel_launch(void* const* d_in, const int* in_sizes, int n_in,
                              void* d_out, int out_size, void* d_ws, size_t ws_size,
                              hipStream_t stream){
  (void)in_sizes; (void)n_in; (void)out_size; (void)ws_size;
  const float* x     = (const float*)d_in[0];
  const float* ln1_g = (const float*)d_in[1];
  const float* ln1_b = (const float*)d_in[2];
  const float* Wq    = (const float*)d_in[3];
  const float* bq    = (const float*)d_in[4];
  const float* Wk    = (const float*)d_in[5];
  const float* bk    = (const float*)d_in[6];
  const float* Wv    = (const float*)d_in[7];
  const float* bv    = (const float*)d_in[8];
  const float* Wo    = (const float*)d_in[9];
  const float* bo    = (const float*)d_in[10];
  const float* proj  = (const float*)d_in[11];
  const float* ln2_g = (const float*)d_in[12];
  const float* ln2_b = (const float*)d_in[13];
  const float* W1    = (const float*)d_in[14];
  const float* b1    = (const float*)d_in[15];
  const float* W2    = (const float*)d_in[16];
  const float* b2    = (const float*)d_in[17];

  float* h = (float*)d_out;
  const size_t MC = (size_t)MROWS*C;
  char* w = (char*)d_ws;
  auto alloc = [&](size_t bytes)->char*{ char* p = w; w += (bytes + 255) & ~(size_t)255; return p; };

  ushort* y16  = (ushort*)alloc(MC*2);
  ushort* qb16 = (ushort*)alloc(MC*2);   // q,k,v contiguous: QKV-fused epilogue indexes bid*MC
  ushort* kb16 = (ushort*)alloc(MC*2);
  ushort* vb16 = (ushort*)alloc(MC*2);
  ushort* o16  = (ushort*)alloc(MC*2);
  ushort* h16  = (ushort*)alloc(MC*2);   // bf16 residual stream (final FF2 writes fp32 d_out)
  ushort* wt   = (ushort*)alloc((size_t)2*2097152*2); // both layers' transposed bf16 weights
  float*  cost = (float*) alloc((size_t)NTOK*16*4);
  float*  sint = (float*) alloc((size_t)NTOK*16*4);
  float*  ctxb = (float*) alloc((size_t)16*NBF*DH*4);
  float*  ksum = (float*) alloc((size_t)16*NBF*4);

  ushort* mid16 = qb16;                    // FFN mid (M*FF bf16 = 32MB) aliases qb16+kb16 (dead)
  float*  ctxp  = (float*)o16;             // ctx partials (7.2MB) alias o16 (written later)
  float*  ksump = ctxp + (size_t)16*32*NBF*DH;

  k_tables<<<(NTOK*16 + 255)/256, 256, 0, stream>>>(cost, sint);
  k_wcvt_all<<<4096, 256, 0, stream>>>(Wq, Wk, Wv, Wo, W1, W2, wt);

  dim3 blkg(512);
  dim3 g512(4, 64);     // N=512  (nwg=256)
  dim3 gqkv(12, 64);    // N=1536 fused (nwg=768)
  dim3 gff(8, 64);      // N=1024 (nwg=512)

  for (int l = 0; l < 2; l++){
    const float* pj = proj + (size_t)l*NBF*DH;
    ushort* wl  = wt + (size_t)l*2097152;
    ushort* wtq = wl;
    ushort* wto = wl +  786432;
    ushort* wt1 = wl + 1048576;
    ushort* wt2 = wl + 1572864;

    if (l == 0) k_ln<0><<<MROWS, 256, 0, stream>>>(x,   ln1_g + l*C, ln1_b + l*C, y16);
    else        k_ln<1><<<MROWS, 256, 0, stream>>>(h16, ln1_g + l*C, ln1_b + l*C, y16);
    k_mgemm<0,1,1,0><<<gqkv, blkg, 0, stream>>>(y16, wtq, bq + l*C, bk + l*C, bv + l*C,
                                                nullptr, nullptr, qb16, cost, sint, 1536, C);
    k_ctx3<<<16*32, 256, 0, stream>>>(kb16, vb16, pj, ctxp, ksump);
    k_ctxred<<<16*NBF, 64, 0, stream>>>(ctxp, ksump, ctxb, ksum);
    k_qattn3<<<16*128, 256, 0, stream>>>(qb16, pj, ctxb, ksum, o16);
    k_local2<<<BATCH*8*NW, 256, 0, stream>>>(qb16, kb16, vb16, o16);
    // Wo + residual: layer0 residual = x (fp32), layer1 residual = h16 (bf16); out h16.
    if (l == 0)
      k_mgemm<0,1,0,0><<<g512, blkg, 0, stream>>>(o16, wto, bo + l*C, nullptr, nullptr,
                                                  x, nullptr, h16, nullptr, nullptr, C, C);
    else
      k_mgemm<0,1,0,1><<<g512, blkg, 0, stream>>>(o16, wto, bo + l*C, nullptr, nullptr,
                                                  h16, nullptr, h16, nullptr, nullptr, C, C);
    k_ln<1><<<MROWS, 256, 0, stream>>>(h16, ln2_g + l*C, ln2_b + l*C, y16);
    k_mgemm<1,1,0,0><<<gff, blkg, 0, stream>>>(y16, wt1, b1 + l*FF, nullptr, nullptr, nullptr,
                                               nullptr, mid16, nullptr, nullptr, FF, C);
    // FF2 + residual h16: layer0 -> h16 (bf16), layer1 -> h (fp32 d_out).
    if (l == 0)
      k_mgemm<0,1,0,1><<<g512, blkg, 0, stream>>>(mid16, wt2, b2 + l*C, nullptr, nullptr,
                                                  h16, nullptr, h16, nullptr, nullptr, C, FF);
    else
      k_mgemm<0,0,0,1><<<g512, blkg, 0, stream>>>(mid16, wt2, b2 + l*C, nullptr, nullptr,
                                                  h16, h, nullptr, nullptr, nullptr, C, FF);
  }
}

// Round 17
// 477.412 us; speedup vs baseline: 1.0090x; 1.0090x over previous
//
#include <hip/hip_runtime.h>
#include <math.h>

namespace {

constexpr int BATCH = 2;
constexpr int NTOK  = 8192;    // tokens per batch (T*H*W)
constexpr int MROWS = 16384;   // BATCH*NTOK
constexpr int C     = 512;
constexpr int GH    = 8;
constexpr int DH    = 32;
constexpr int WIN   = 64;
constexpr int NW    = 128;     // NTOK/WIN
constexpr int FF    = 1024;
constexpr int NBF   = 110;     // int(32*ln(32))
constexpr int NBFP  = 128;     // padded feature count (MFMA tiles)

constexpr float F_DN     = 0.42044820762685725f;   // 32^-0.25
constexpr float F_RNORM  = 0.09534625892455924f;   // 110^-0.5
constexpr float F_LSCALE = 0.17677669529663687f;   // 32^-0.5

typedef __attribute__((ext_vector_type(8))) short bf16x8;
typedef __attribute__((ext_vector_type(4))) float f32x4;

__device__ __forceinline__ ushort f2b(float f){
  unsigned u = __float_as_uint(f);
  unsigned r = u + 0x7FFFu + ((u >> 16) & 1u);
  return (ushort)(r >> 16);
}
__device__ __forceinline__ float b2f(ushort u){
  return __uint_as_float((unsigned)u << 16);
}

__device__ __forceinline__ void gload16(const void* g, void* l){
  __builtin_amdgcn_global_load_lds((const __attribute__((address_space(1))) void*)g,
                                   (__attribute__((address_space(3))) void*)l, 16, 0, 0);
}

__global__ void k_tables(float* __restrict__ cost, float* __restrict__ sint){
  int idx = blockIdx.x*256 + threadIdx.x;
  if (idx >= NTOK*16) return;
  int pos = idx >> 4, f = idx & 15;
  float inv = powf(10000.f, -(float)f/16.f);
  float ang = (float)pos * inv;
  cost[idx] = cosf(ang);
  sint[idx] = sinf(ang);
}

// All 12 weight matrices (both layers) fp32 (K,N) -> bf16 transposed (N,K), one dispatch.
__global__ __launch_bounds__(256) void k_wcvt_all(const float* __restrict__ Wq, const float* __restrict__ Wk,
     const float* __restrict__ Wv, const float* __restrict__ Wo, const float* __restrict__ W1,
     const float* __restrict__ W2, ushort* __restrict__ wt){
  __shared__ float t[32][33];
  int id = blockIdx.x;
  int l = id >> 11;
  int r = id & 2047;
  const float* src; ushort* dst; int K, N, bx, by;
  if (r < 1024){
    int mat = r >> 8, tt = r & 255;
    bx = tt & 15; by = tt >> 4; K = 512; N = 512;
    src = ((mat == 0) ? Wq : (mat == 1) ? Wk : (mat == 2) ? Wv : Wo) + (size_t)l*262144;
    dst = wt + (size_t)l*2097152 + (size_t)mat*262144;
  } else if (r < 1536){
    int tt = r - 1024;
    bx = tt & 31; by = tt >> 5; K = 512; N = 1024;
    src = W1 + (size_t)l*524288;
    dst = wt + (size_t)l*2097152 + 1048576;
  } else {
    int tt = r - 1536;
    bx = tt & 15; by = tt >> 4; K = 1024; N = 512;
    src = W2 + (size_t)l*524288;
    dst = wt + (size_t)l*2097152 + 1572864;
  }
  int tx = threadIdx.x & 31, ty = threadIdx.x >> 5;
  #pragma unroll
  for (int rr = ty; rr < 32; rr += 8) t[rr][tx] = src[(size_t)(by*32+rr)*N + bx*32 + tx];
  __syncthreads();
  #pragma unroll
  for (int rr = ty; rr < 32; rr += 8) dst[(size_t)(bx*32+rr)*K + by*32 + tx] = f2b(t[tx][rr]);
}

// LayerNorm; INBF: input is bf16 (residual stream) vs fp32.
template<int INBF>
__global__ __launch_bounds__(256) void k_ln(const void* __restrict__ xv, const float* __restrict__ g,
                     const float* __restrict__ b, ushort* __restrict__ y){
  int row = blockIdx.x, t = threadIdx.x;
  float2 v;
  if (INBF){
    ushort2 u = *(const ushort2*)((const ushort*)xv + (size_t)row*C + 2*t);
    v.x = b2f(u.x); v.y = b2f(u.y);
  } else {
    v = *(const float2*)((const float*)xv + (size_t)row*C + 2*t);
  }
  float s = v.x + v.y, ss = v.x*v.x + v.y*v.y;
  #pragma unroll
  for (int o = 32; o; o >>= 1){ s += __shfl_down(s, o); ss += __shfl_down(ss, o); }
  __shared__ float rs[4], rss[4];
  int wv = t >> 6, ln = t & 63;
  if (ln == 0){ rs[wv] = s; rss[wv] = ss; }
  __syncthreads();
  float S = rs[0]+rs[1]+rs[2]+rs[3], SS = rss[0]+rss[1]+rss[2]+rss[3];
  float mean = S * (1.f/C);
  float var  = SS * (1.f/C) - mean*mean;
  float rstd = rsqrtf(var + 1e-5f);
  float2 gg = *(const float2*)(g + 2*t);
  float2 bb = *(const float2*)(b + 2*t);
  ushort2 ov;
  ov.x = f2b((v.x - mean)*rstd*gg.x + bb.x);
  ov.y = f2b((v.y - mean)*rstd*gg.y + bb.y);
  *(ushort2*)(y + (size_t)row*C + 2*t) = ov;
}

// bf16 MFMA GEMM v3 (large): 256x128 tile, 8 waves, 2-phase dbuf, T1 XCD swizzle.
// Used for QKV (N=1536) and FF1 (N=1024) where grid >= 2 blocks/CU.
// A: (M,K) bf16 row-major.  Bt: (N,K) bf16 row-major.  grid (Nd/128, M/256).
// QKV==1: Nd=1536 logical; de-interleave into 3 (M,512) buffers + fused RoPE.
template<int ACT, int OBF, int QKV, int RESBF>
__global__ __launch_bounds__(512) void k_mgemm(const ushort* __restrict__ A, const ushort* __restrict__ Bt,
      const float* __restrict__ bias, const float* __restrict__ bias2, const float* __restrict__ bias3,
      const void* __restrict__ res, float* __restrict__ outf, ushort* __restrict__ outb,
      const float* __restrict__ cosT, const float* __restrict__ sinT, int Nd, int Kd){
  __shared__ ushort As[2][256*32];   // 16KB per buffer
  __shared__ ushort Bs[2][128*32];   //  8KB per buffer
  int tid = threadIdx.x;
  int lane = tid & 63, wave = tid >> 6;      // 8 waves
  int c = lane & 15, g = lane >> 4;
  int wr = wave >> 1, wc = wave & 1;         // 4M x 2N wave grid
  // T1: XCD-bijective swizzle (all grids have nwg % 8 == 0).
  int gx = gridDim.x;
  int nwg = gx * (int)gridDim.y;
  int bid = (int)(blockIdx.y*gx + blockIdx.x);
  int swz = (bid & 7)*(nwg >> 3) + (bid >> 3);
  int row0 = (swz / gx)*256, col0 = (swz % gx)*128;
  f32x4 acc[4][4] = {};
  int nt = Kd >> 5;

  #define STAGE(buf, kt) {                                                        \
    int k0_ = (kt)*32;                                                            \
    _Pragma("unroll")                                                             \
    for (int j = 0; j < 2; j++){                                                  \
      int ci = j*512 + tid;                                                       \
      gload16(A + (size_t)(row0 + (ci>>2))*Kd + k0_ + (ci&3)*8,                   \
              (char*)As[buf] + (j*512 + wave*64)*16);                             \
    }                                                                             \
    {                                                                             \
      int ci = tid;                                                               \
      gload16(Bt + (size_t)(col0 + (ci>>2))*Kd + k0_ + (ci&3)*8,                  \
              (char*)Bs[buf] + (wave*64)*16);                                     \
    }                                                                             \
  }

  STAGE(0, 0);
  __syncthreads();                                  // drain tile-0 loads

  for (int t = 0; t < nt; t++){
    int cur = t & 1;
    bf16x8 af[4], bfr[4];
    #pragma unroll
    for (int m = 0; m < 4; m++)
      af[m] = *(const bf16x8*)(As[cur] + (wr*64 + m*16 + c)*32 + g*8);
    #pragma unroll
    for (int n = 0; n < 4; n++)
      bfr[n] = *(const bf16x8*)(Bs[cur] + (wc*64 + n*16 + c)*32 + g*8);
    if (t + 1 < nt) STAGE(cur^1, t+1);              // loads fly under the MFMAs
    __builtin_amdgcn_s_setprio(1);
    #pragma unroll
    for (int m = 0; m < 4; m++)
      #pragma unroll
      for (int n = 0; n < 4; n++)
        acc[m][n] = __builtin_amdgcn_mfma_f32_16x16x32_bf16(af[m], bfr[n], acc[m][n], 0, 0, 0);
    __builtin_amdgcn_s_setprio(0);
    __syncthreads();                                // post-MFMA drain + LDS reuse barrier
  }
  #undef STAGE

  if (QKV){
    #pragma unroll
    for (int m = 0; m < 4; m++){
      int rbase = row0 + wr*64 + m*16 + g*4;
      #pragma unroll
      for (int np = 0; np < 2; np++){
        int n0 = 2*np, n1 = n0 + 1;
        int ccol = col0 + wc*64 + n0*16 + c;           // ccol&31 == c (<16)
        int bid2 = ccol >> 9;
        int cl  = ccol & 511;
        const float* bp = (bid2 == 0) ? bias : (bid2 == 1) ? bias2 : bias3;
        float b0 = bp[cl], b1 = bp[cl+16];
        bool dorope = (bid2 < 2) && (cl >= 256);
        ushort* obase = outb + (size_t)bid2*MROWS*C;
        #pragma unroll
        for (int r = 0; r < 4; r++){
          int grow = rbase + r;
          float a  = acc[m][n0][r] + b0;
          float bb = acc[m][n1][r] + b1;
          if (dorope){
            int pos = grow & (NTOK-1);
            float cv = cosT[pos*16 + c], sv = sinT[pos*16 + c];
            float na = a*cv - bb*sv;
            float nb = bb*cv + a*sv;
            a = na; bb = nb;
          }
          obase[(size_t)grow*C + cl]      = f2b(a);
          obase[(size_t)grow*C + cl + 16] = f2b(bb);
        }
      }
    }
    return;
  }
  #pragma unroll
  for (int m = 0; m < 4; m++){
    int rbase = row0 + wr*64 + m*16 + g*4;
    #pragma unroll
    for (int n = 0; n < 4; n++){
      int ccol = col0 + wc*64 + n*16 + c;
      float bv = bias[ccol];
      #pragma unroll
      for (int r = 0; r < 4; r++){
        int grow = rbase + r;
        float vv = acc[m][n][r] + bv;
        if (ACT == 1) vv = 0.5f*vv*(1.f + erff(vv*0.7071067811865476f));
        if (res){
          size_t ri = (size_t)grow*Nd + ccol;
          vv += RESBF ? b2f(((const ushort*)res)[ri]) : ((const float*)res)[ri];
        }
        if (OBF) outb[(size_t)grow*Nd + ccol] = f2b(vv);
        else     outf[(size_t)grow*Nd + ccol] = vv;
      }
    }
  }
}

// bf16 MFMA GEMM (small): 128x128 tile, 4 waves, 2-phase dbuf (R13-proven), T1 swizzle.
// Used for Wo/FF2 (N=512): grid 4x128 = 512 blocks = 2/CU resident (vs 1/CU at 256-tile).
template<int ACT, int OBF, int RESBF>
__global__ __launch_bounds__(256) void k_mgemm_s(const ushort* __restrict__ A, const ushort* __restrict__ Bt,
      const float* __restrict__ bias, const void* __restrict__ res,
      float* __restrict__ outf, ushort* __restrict__ outb, int Nd, int Kd){
  __shared__ ushort As[2][128*32];
  __shared__ ushort Bs[2][128*32];
  int tid = threadIdx.x;
  int lane = tid & 63, wave = tid >> 6;
  int wr = wave >> 1, wc = wave & 1;
  int gx = gridDim.x;
  int nwg = gx * (int)gridDim.y;
  int bid = (int)(blockIdx.y*gx + blockIdx.x);
  int swz = (bid & 7)*(nwg >> 3) + (bid >> 3);
  int row0 = (swz / gx)*128, col0 = (swz % gx)*128;
  f32x4 acc[4][4] = {};
  int nt = Kd >> 5;

  #define STAGE(buf, kt) {                                                        \
    int k0_ = (kt)*32;                                                            \
    _Pragma("unroll")                                                             \
    for (int cc = 0; cc < 2; cc++){                                               \
      int off = (wave*2 + cc)*1024 + lane*16;                                     \
      int r_ = off >> 6, ke_ = (off & 63) >> 1;                                   \
      gload16(A  + (size_t)(row0 + r_)*Kd + k0_ + ke_,                            \
              (char*)As[buf] + (wave*2 + cc)*1024);                               \
      gload16(Bt + (size_t)(col0 + r_)*Kd + k0_ + ke_,                            \
              (char*)Bs[buf] + (wave*2 + cc)*1024);                               \
    }                                                                             \
  }

  STAGE(0, 0);
  __syncthreads();

  for (int t = 0; t < nt; t++){
    int cur = t & 1;
    bf16x8 af[4], bfr[4];
    #pragma unroll
    for (int m = 0; m < 4; m++)
      af[m] = *(const bf16x8*)((const char*)As[cur] + (wr*64 + m*16 + (lane&15))*64 + (lane>>4)*16);
    #pragma unroll
    for (int n = 0; n < 4; n++)
      bfr[n] = *(const bf16x8*)((const char*)Bs[cur] + (wc*64 + n*16 + (lane&15))*64 + (lane>>4)*16);
    if (t + 1 < nt) STAGE(cur^1, t+1);
    __builtin_amdgcn_s_setprio(1);
    #pragma unroll
    for (int m = 0; m < 4; m++)
      #pragma unroll
      for (int n = 0; n < 4; n++)
        acc[m][n] = __builtin_amdgcn_mfma_f32_16x16x32_bf16(af[m], bfr[n], acc[m][n], 0, 0, 0);
    __builtin_amdgcn_s_setprio(0);
    __syncthreads();
  }
  #undef STAGE

  #pragma unroll
  for (int m = 0; m < 4; m++){
    int rbase = row0 + wr*64 + m*16 + (lane>>4)*4;
    #pragma unroll
    for (int n = 0; n < 4; n++){
      int ccol = col0 + wc*64 + n*16 + (lane&15);
      float bv = bias[ccol];
      #pragma unroll
      for (int r = 0; r < 4; r++){
        int grow = rbase + r;
        float vv = acc[m][n][r] + bv;
        if (ACT == 1) vv = 0.5f*vv*(1.f + erff(vv*0.7071067811865476f));
        if (res){
          size_t ri = (size_t)grow*Nd + ccol;
          vv += RESBF ? b2f(((const ushort*)res)[ri]) : ((const float*)res)[ri];
        }
        if (OBF) outb[(size_t)grow*Nd + ccol] = f2b(vv);
        else     outf[(size_t)grow*Nd + ccol] = vv;
      }
    }
  }
}

// Performer K side v4 (MFMA, no global-stab pass). Block = (bh, 256 k-rows); 4 waves.
__global__ __launch_bounds__(256) void k_ctx3(const ushort* __restrict__ k, const ushort* __restrict__ v,
        const float* __restrict__ proj, float* __restrict__ ctxp, float* __restrict__ ksump){
  int bh = blockIdx.x >> 5, chunk = blockIdx.x & 31;
  int b = bh >> 3, h = bh & 7;
  __shared__ __align__(16) ushort pl[NBFP*40];   // proj bf16 [feat][40 pad]  10.0KB
  __shared__ __align__(16) ushort Ps[NBFP*72];   // P [feat][64+8 pad]        18.0KB
  __shared__ __align__(16) ushort Vt[48*72];     // V^T slice [48][72]         6.75KB
  __shared__ float dgl[256];
  int tid = threadIdx.x;
  int lane = tid & 63, wave = tid >> 6;
  int c = lane & 15, g = lane >> 4;
  int i0 = chunk*256;

  for (int idx = tid; idx < NBFP*32; idx += 256){
    int f = idx >> 5, d = idx & 31;
    pl[f*40 + d] = (f < NBF) ? f2b(proj[f*32 + d]*F_DN) : (ushort)0;
  }
  const ushort* kbase = k + ((size_t)b*NTOK + i0)*C + h*DH;
  const ushort* vbase = v + ((size_t)b*NTOK + i0)*C + h*DH;
  #pragma unroll
  for (int s = 0; s < 4; s++){
    bf16x8 kf = *(const bf16x8*)(kbase + (size_t)(s*64 + wave*16 + c)*C + g*8);
    const ushort* kp_ = (const ushort*)&kf;
    float sq = 0.f;
    #pragma unroll
    for (int j = 0; j < 8; j++){ float vv = b2f(kp_[j]); sq += vv*vv; }
    sq += __shfl_xor(sq, 16);
    sq += __shfl_xor(sq, 32);
    if (g == 0) dgl[s*64 + wave*16 + c] = 0.5f*F_DN*F_DN*sq;
  }
  for (int idx = tid; idx < 15*72; idx += 256) Vt[33*72 + idx] = 0;   // zero rows 33..47

  f32x4 zz = {0.f, 0.f, 0.f, 0.f};
  f32x4 acc[2][3] = {};

  for (int s = 0; s < 4; s++){
    __syncthreads();     // Ps/Vt free (also covers pl/dgl/Vt-zero init at s=0)
    {
      int r = tid >> 2, part = tid & 3;
      uint4 vv = *(const uint4*)(vbase + (size_t)(s*64 + r)*C + part*8);
      const ushort* vp = (const ushort*)&vv;
      #pragma unroll
      for (int j = 0; j < 8; j++) Vt[(part*8+j)*72 + r] = vp[j];
      if (tid < 64) Vt[32*72 + tid] = 0x3F80;   // bf16 1.0
    }
    bf16x8 af = *(const bf16x8*)(kbase + (size_t)(s*64 + wave*16 + c)*C + g*8);
    #pragma unroll
    for (int ft = 0; ft < 8; ft++){
      bf16x8 bf = *(const bf16x8*)(pl + (ft*16 + c)*40 + g*8);
      f32x4 dd = __builtin_amdgcn_mfma_f32_16x16x32_bf16(af, bf, zz, 0, 0, 0);
      int feat = ft*16 + c;
      bool fvalid = feat < NBF;
      ushort pb[4];
      #pragma unroll
      for (int r = 0; r < 4; r++){
        float kp = 0.f;
        if (fvalid){
          float dg_ = dgl[s*64 + wave*16 + g*4 + r];
          kp = F_RNORM*(__expf(dd[r] - dg_) + 1e-4f);
        }
        pb[r] = f2b(kp);
      }
      uint2 pd;
      pd.x = (unsigned)pb[0] | ((unsigned)pb[1] << 16);
      pd.y = (unsigned)pb[2] | ((unsigned)pb[3] << 16);
      *(uint2*)(Ps + (ft*16 + c)*72 + wave*16 + g*4) = pd;
    }
    __syncthreads();
    #pragma unroll
    for (int i = 0; i < 2; i++){
      int ft = wave*2 + i;
      #pragma unroll
      for (int kk = 0; kk < 2; kk++){
        bf16x8 ap = *(const bf16x8*)(Ps + (ft*16 + c)*72 + kk*32 + g*8);
        #pragma unroll
        for (int nt = 0; nt < 3; nt++){
          bf16x8 bv = *(const bf16x8*)(Vt + (nt*16 + c)*72 + kk*32 + g*8);
          acc[i][nt] = __builtin_amdgcn_mfma_f32_16x16x32_bf16(ap, bv, acc[i][nt], 0, 0, 0);
        }
      }
    }
  }
  size_t pbase = (size_t)(bh*32 + chunk)*NBF;
  #pragma unroll
  for (int i = 0; i < 2; i++){
    int ftb = (wave*2 + i)*16;
    #pragma unroll
    for (int r = 0; r < 4; r++){
      int feat = ftb + g*4 + r;
      if (feat < NBF){
        #pragma unroll
        for (int nt = 0; nt < 2; nt++)
          ctxp[(pbase + feat)*DH + nt*16 + c] = acc[i][nt][r];
        if (c == 0) ksump[pbase + feat] = acc[i][2][r];
      }
    }
  }
}

__global__ void k_ctxred(const float* __restrict__ ctxp, const float* __restrict__ ksump,
                         float* __restrict__ ctx, float* __restrict__ ksum){
  int bh = blockIdx.x / NBF, m = blockIdx.x % NBF;
  int t = threadIdx.x;
  if (t < DH){
    float s = 0.f;
    for (int c = 0; c < 32; c++) s += ctxp[((size_t)(bh*32 + c)*NBF + m)*DH + t];
    ctx[((size_t)bh*NBF + m)*DH + t] = s;
  } else if (t == DH){
    float s = 0.f;
    for (int c = 0; c < 32; c++) s += ksump[(size_t)(bh*32 + c)*NBF + m];
    ksum[bh*NBF + m] = s;
  }
}

// Performer Q side v3 (MFMA). One block per (bh, 64 q-rows); 4 waves.
__global__ __launch_bounds__(256) void k_qattn3(const ushort* __restrict__ q, const float* __restrict__ proj,
        const float* __restrict__ ctx, const float* __restrict__ ksum, ushort* __restrict__ o){
  int bh = blockIdx.x >> 7, chunk = blockIdx.x & 127;
  int b = bh >> 3, h = bh & 7;
  __shared__ __align__(16) ushort pl[NBFP*40];    // proj bf16 [feat][40 pad]   10.0KB
  __shared__ __align__(16) ushort ql[64*40];      // Q [qrow][40 pad]            5.0KB
  __shared__ __align__(16) ushort ctl[32*136];    // ctx^T [d][136 pad]          8.5KB
  __shared__ __align__(16) ushort Ps[64*136];     // P [qrow][136 pad]          17.0KB
  __shared__ float ksl[NBFP];
  __shared__ float dgl[64];
  __shared__ float dvl[64];
  int tid = threadIdx.x;
  int lane = tid & 63, wave = tid >> 6;
  int c = lane & 15, g = lane >> 4;
  int i0 = chunk*64;

  for (int idx = tid; idx < NBFP*32; idx += 256){
    int f = idx >> 5, d = idx & 31;
    pl[f*40 + d] = (f < NBF) ? f2b(proj[f*32 + d]*F_DN) : (ushort)0;
  }
  {
    int row = tid >> 2, part = tid & 3;
    uint4 qq = *(const uint4*)(q + (size_t)(b*NTOK + i0 + row)*C + h*DH + part*8);
    *(uint4*)(ql + row*40 + part*8) = qq;
    const ushort* qp_ = (const ushort*)&qq;
    float sq = 0.f;
    #pragma unroll
    for (int j = 0; j < 8; j++){ float vv = b2f(qp_[j]); sq += vv*vv; }
    sq += __shfl_xor(sq, 1);
    sq += __shfl_xor(sq, 2);
    if (part == 0) dgl[row] = 0.5f*F_DN*F_DN*sq;
  }
  for (int idx = tid; idx < 32*NBFP; idx += 256){
    int d = idx >> 7, f = idx & 127;
    float vv = (f < NBF) ? ctx[((size_t)bh*NBF + f)*DH + d] : 0.f;
    ctl[d*136 + f] = f2b(vv);
  }
  if (tid < NBFP) ksl[tid] = (tid < NBF) ? ksum[bh*NBF + tid] : 0.f;
  __syncthreads();

  f32x4 zz = {0.f, 0.f, 0.f, 0.f};
  bf16x8 qf = *(const bf16x8*)(ql + (wave*16 + c)*40 + g*8);
  f32x4 st[8];
  #pragma unroll
  for (int mt = 0; mt < 8; mt++){
    bf16x8 af = *(const bf16x8*)(pl + (mt*16 + c)*40 + g*8);
    st[mt] = __builtin_amdgcn_mfma_f32_16x16x32_bf16(af, qf, zz, 0, 0, 0);
  }
  float mx = -1e30f;
  #pragma unroll
  for (int mt = 0; mt < 8; mt++)
    #pragma unroll
    for (int r = 0; r < 4; r++){
      int feat = mt*16 + g*4 + r;
      if (feat < NBF) mx = fmaxf(mx, st[mt][r]);
    }
  mx = fmaxf(mx, __shfl_xor(mx, 16));
  mx = fmaxf(mx, __shfl_xor(mx, 32));
  float diagv = dgl[wave*16 + c];
  float dv = 0.f;
  #pragma unroll
  for (int mt = 0; mt < 8; mt++){
    ushort pb[4];
    #pragma unroll
    for (int r = 0; r < 4; r++){
      int feat = mt*16 + g*4 + r;
      float qp = 0.f;
      if (feat < NBF) qp = F_RNORM*(__expf(st[mt][r] - diagv - mx) + 1e-4f);
      ushort qb = f2b(qp);
      pb[r] = qb;
      dv += b2f(qb)*ksl[feat];
    }
    uint2 pd;
    pd.x = (unsigned)pb[0] | ((unsigned)pb[1] << 16);
    pd.y = (unsigned)pb[2] | ((unsigned)pb[3] << 16);
    *(uint2*)(Ps + (wave*16 + c)*136 + mt*16 + g*4) = pd;
  }
  dv += __shfl_xor(dv, 16);
  dv += __shfl_xor(dv, 32);
  if (g == 0) dvl[wave*16 + c] = 1.f/dv;
  __syncthreads();

  #pragma unroll
  for (int n = 0; n < 2; n++){
    f32x4 acc = zz;
    #pragma unroll
    for (int kk = 0; kk < 4; kk++){
      bf16x8 ap = *(const bf16x8*)(Ps  + (wave*16 + c)*136 + kk*32 + g*8);
      bf16x8 bc = *(const bf16x8*)(ctl + (n*16 + c)*136    + kk*32 + g*8);
      acc = __builtin_amdgcn_mfma_f32_16x16x32_bf16(ap, bc, acc, 0, 0, 0);
    }
    #pragma unroll
    for (int r = 0; r < 4; r++){
      int qrow = wave*16 + g*4 + r;
      float val = acc[r]*dvl[qrow];
      o[(size_t)(b*NTOK + i0 + qrow)*C + h*DH + n*16 + c] = f2b(val);
    }
  }
}

// Local windowed attention via MFMA. One block per (b, head, window); 4 waves x 16 q-rows.
__global__ __launch_bounds__(256) void k_local2(const ushort* __restrict__ q, const ushort* __restrict__ k,
        const ushort* __restrict__ v, ushort* __restrict__ o){
  int blk = blockIdx.x;
  int w = blk & (NW-1);
  int rem = blk >> 7;
  int hl = rem & 7, b = rem >> 3;
  int hd = GH + hl;
  __shared__ __align__(16) ushort Ks[192*32];      // [key][d]        12.0KB
  __shared__ __align__(16) ushort Vt[32*200];      // [d][key] pad    12.5KB
  __shared__ __align__(16) ushort Ps[4*16*200];    // per-wave [q][key] pad 25KB
  int tid = threadIdx.x;
  int lane = tid & 63, wave = tid >> 6;
  int c = lane & 15, g = lane >> 4;

  const ushort* kbase = k + (size_t)b*NTOK*C + hd*DH;
  const ushort* vbase = v + (size_t)b*NTOK*C + hd*DH;
  #pragma unroll
  for (int s = 0; s < 3; s++){
    int ch = tid + s*256;
    int row = ch >> 2, part = ch & 3;
    int kp = min(max((w-1)*WIN + row, 0), NTOK-1);
    gload16(kbase + (size_t)kp*C + part*8, (char*)Ks + (s*256 + wave*64)*16);
  }
  #pragma unroll
  for (int s = 0; s < 3; s++){
    int ch = tid + s*256;
    int row = ch >> 2, part = ch & 3;
    int kp = min(max((w-1)*WIN + row, 0), NTOK-1);
    uint4 vv = *(const uint4*)(vbase + (size_t)kp*C + part*8);
    const ushort* vp = (const ushort*)&vv;
    #pragma unroll
    for (int j = 0; j < 8; j++) Vt[(part*8+j)*200 + row] = vp[j];
  }
  int qrow = w*WIN + wave*16 + c;
  bf16x8 qf = *(const bf16x8*)(q + ((size_t)b*NTOK + qrow)*C + hd*DH + g*8);
  asm volatile("s_waitcnt vmcnt(0)" ::: "memory");
  __syncthreads();

  f32x4 zz = {0.f, 0.f, 0.f, 0.f};
  f32x4 st[12];
  #pragma unroll
  for (int t = 0; t < 12; t++){
    bf16x8 af = *(const bf16x8*)(Ks + (16*t + c)*32 + g*8);
    st[t] = __builtin_amdgcn_mfma_f32_16x16x32_bf16(af, qf, zz, 0, 0, 0);
  }
  int t0 = (w == 0) ? 4 : 0;
  int t1 = (w == NW-1) ? 8 : 12;
  float lsum = 0.f;
  ushort* pw = Ps + wave*3200 + c*200;
  #pragma unroll
  for (int t = 0; t < 12; t++){
    bool valid = (t >= t0) && (t < t1);
    float p0 = valid ? __expf(st[t][0]*F_LSCALE) : 0.f;
    float p1 = valid ? __expf(st[t][1]*F_LSCALE) : 0.f;
    float p2 = valid ? __expf(st[t][2]*F_LSCALE) : 0.f;
    float p3 = valid ? __expf(st[t][3]*F_LSCALE) : 0.f;
    lsum += (p0+p1)+(p2+p3);
    uint2 pd;
    pd.x = (unsigned)f2b(p0) | ((unsigned)f2b(p1) << 16);
    pd.y = (unsigned)f2b(p2) | ((unsigned)f2b(p3) << 16);
    *(uint2*)(pw + 16*t + 4*g) = pd;
  }
  lsum += __shfl_xor(lsum, 16);
  lsum += __shfl_xor(lsum, 32);

  f32x4 oc0 = zz, oc1 = zz;
  #pragma unroll
  for (int kb = 0; kb < 6; kb++){
    bf16x8 pf = *(const bf16x8*)(pw + kb*32 + g*8);
    bf16x8 v0 = *(const bf16x8*)(Vt + c*200 + kb*32 + g*8);
    bf16x8 v1 = *(const bf16x8*)(Vt + (16 + c)*200 + kb*32 + g*8);
    oc0 = __builtin_amdgcn_mfma_f32_16x16x32_bf16(v0, pf, oc0, 0, 0, 0);
    oc1 = __builtin_amdgcn_mfma_f32_16x16x32_bf16(v1, pf, oc1, 0, 0, 0);
  }
  float inv = 1.f/lsum;
  ushort* orow = o + ((size_t)b*NTOK + qrow)*C + hd*DH;
  uint2 w0, w1;
  w0.x = (unsigned)f2b(oc0[0]*inv) | ((unsigned)f2b(oc0[1]*inv) << 16);
  w0.y = (unsigned)f2b(oc0[2]*inv) | ((unsigned)f2b(oc0[3]*inv) << 16);
  w1.x = (unsigned)f2b(oc1[0]*inv) | ((unsigned)f2b(oc1[1]*inv) << 16);
  w1.y = (unsigned)f2b(oc1[2]*inv) | ((unsigned)f2b(oc1[3]*inv) << 16);
  *(uint2*)(orow + 4*g)      = w0;
  *(uint2*)(orow + 16 + 4*g) = w1;
}

} // namespace

extern "C" void kernel_launch(void* const* d_in, const int* in_sizes, int n_in,
                              void* d_out, int out_size, void* d_ws, size_t ws_size,
                              hipStream_t stream){
  (void)in_sizes; (void)n_in; (void)out_size; (void)ws_size;
  const float* x     = (const float*)d_in[0];
  const float* ln1_g = (const float*)d_in[1];
  const float* ln1_b = (const float*)d_in[2];
  const float* Wq    = (const float*)d_in[3];
  const float* bq    = (const float*)d_in[4];
  const float* Wk    = (const float*)d_in[5];
  const float* bk    = (const float*)d_in[6];
  const float* Wv    = (const float*)d_in[7];
  const float* bv    = (const float*)d_in[8];
  const float* Wo    = (const float*)d_in[9];
  const float* bo    = (const float*)d_in[10];
  const float* proj  = (const float*)d_in[11];
  const float* ln2_g = (const float*)d_in[12];
  const float* ln2_b = (const float*)d_in[13];
  const float* W1    = (const float*)d_in[14];
  const float* b1    = (const float*)d_in[15];
  const float* W2    = (const float*)d_in[16];
  const float* b2    = (const float*)d_in[17];

  float* h = (float*)d_out;
  const size_t MC = (size_t)MROWS*C;
  char* w = (char*)d_ws;
  auto alloc = [&](size_t bytes)->char*{ char* p = w; w += (bytes + 255) & ~(size_t)255; return p; };

  ushort* y16  = (ushort*)alloc(MC*2);
  ushort* qb16 = (ushort*)alloc(MC*2);   // q,k,v contiguous: QKV-fused epilogue indexes bid*MC
  ushort* kb16 = (ushort*)alloc(MC*2);
  ushort* vb16 = (ushort*)alloc(MC*2);
  ushort* o16  = (ushort*)alloc(MC*2);
  ushort* h16  = (ushort*)alloc(MC*2);   // bf16 residual stream (final FF2 writes fp32 d_out)
  ushort* wt   = (ushort*)alloc((size_t)2*2097152*2); // both layers' transposed bf16 weights
  float*  cost = (float*) alloc((size_t)NTOK*16*4);
  float*  sint = (float*) alloc((size_t)NTOK*16*4);
  float*  ctxb = (float*) alloc((size_t)16*NBF*DH*4);
  float*  ksum = (float*) alloc((size_t)16*NBF*4);

  ushort* mid16 = qb16;                    // FFN mid (M*FF bf16 = 32MB) aliases qb16+kb16 (dead)
  float*  ctxp  = (float*)o16;             // ctx partials (7.2MB) alias o16 (written later)
  float*  ksump = ctxp + (size_t)16*32*NBF*DH;

  k_tables<<<(NTOK*16 + 255)/256, 256, 0, stream>>>(cost, sint);
  k_wcvt_all<<<4096, 256, 0, stream>>>(Wq, Wk, Wv, Wo, W1, W2, wt);

  dim3 blkg(512);
  dim3 blks(256);
  dim3 g512s(4, 128);   // N=512, 128-tile (nwg=512, 2 blocks/CU)
  dim3 gqkv(12, 64);    // N=1536 fused, 256-tile (nwg=768, 3 blocks/CU)
  dim3 gff(8, 64);      // N=1024, 256-tile (nwg=512, 2 blocks/CU)

  for (int l = 0; l < 2; l++){
    const float* pj = proj + (size_t)l*NBF*DH;
    ushort* wl  = wt + (size_t)l*2097152;
    ushort* wtq = wl;
    ushort* wto = wl +  786432;
    ushort* wt1 = wl + 1048576;
    ushort* wt2 = wl + 1572864;

    if (l == 0) k_ln<0><<<MROWS, 256, 0, stream>>>(x,   ln1_g + l*C, ln1_b + l*C, y16);
    else        k_ln<1><<<MROWS, 256, 0, stream>>>(h16, ln1_g + l*C, ln1_b + l*C, y16);
    k_mgemm<0,1,1,0><<<gqkv, blkg, 0, stream>>>(y16, wtq, bq + l*C, bk + l*C, bv + l*C,
                                                nullptr, nullptr, qb16, cost, sint, 1536, C);
    k_ctx3<<<16*32, 256, 0, stream>>>(kb16, vb16, pj, ctxp, ksump);
    k_ctxred<<<16*NBF, 64, 0, stream>>>(ctxp, ksump, ctxb, ksum);
    k_qattn3<<<16*128, 256, 0, stream>>>(qb16, pj, ctxb, ksum, o16);
    k_local2<<<BATCH*8*NW, 256, 0, stream>>>(qb16, kb16, vb16, o16);
    // Wo + residual: layer0 residual = x (fp32), layer1 residual = h16 (bf16); out h16.
    if (l == 0)
      k_mgemm_s<0,1,0><<<g512s, blks, 0, stream>>>(o16, wto, bo + l*C, x, nullptr, h16, C, C);
    else
      k_mgemm_s<0,1,1><<<g512s, blks, 0, stream>>>(o16, wto, bo + l*C, h16, nullptr, h16, C, C);
    k_ln<1><<<MROWS, 256, 0, stream>>>(h16, ln2_g + l*C, ln2_b + l*C, y16);
    k_mgemm<1,1,0,0><<<gff, blkg, 0, stream>>>(y16, wt1, b1 + l*FF, nullptr, nullptr, nullptr,
                                               nullptr, mid16, nullptr, nullptr, FF, C);
    // FF2 + residual h16: layer0 -> h16 (bf16), layer1 -> h (fp32 d_out).
    if (l == 0)
      k_mgemm_s<0,1,1><<<g512s, blks, 0, stream>>>(mid16, wt2, b2 + l*C, h16, nullptr, h16, C, FF);
    else
      k_mgemm_s<0,0,1><<<g512s, blks, 0, stream>>>(mid16, wt2, b2 + l*C, h16, h, nullptr, C, FF);
  }
}